// Round 6
// baseline (155.908 us; speedup 1.0000x reference)
//
#include <hip/hip_runtime.h>
#include <hip/hip_cooperative_groups.h>
#include <math.h>

namespace cg = cooperative_groups;

#define Bc 8
#define Sc 512
#define Hc 768
#define Ec 16
#define Mc 4
#define Cc 96
#define Pc 240   // E*E - E
#define NB 192   // grid: 192 blocks x 256 threads, co-resident (<=1/CU)

// ws layout (floats):
//   att_rows : B*E*S = 65536
//   cnt      : B*E   = 128
//   docv     : B*E*H = 98304
//   ctxu     : B*E*H = 98304  (atomic-accumulated; zeroed in phase 1)

// Single cooperative kernel, 3 phases separated by grid.sync():
//   P1 (blocks 0..127): per (b,e) mask compaction, count, att_rows,
//       doc logsumexp (two-pass, 4-way MLP), zero ctxu slice.
//   P2 (all 192 blocks): ctxu += att_rows-chunk @ emb-chunk (atomics, 8-way).
//   P3 (all blocks, 10 rows each): assemble float4 output + labels.
__global__ __launch_bounds__(256) void k_fused(
    const float* __restrict__ emb, const float* __restrict__ att,
    const int* __restrict__ starts, const int* __restrict__ lens,
    const int* __restrict__ labels,
    float* __restrict__ att_rows, float* __restrict__ cnt,
    float* __restrict__ docv, float* __restrict__ ctxu,
    float* __restrict__ out)
{
  cg::grid_group gg = cg::this_grid();
  const int bid = blockIdx.x;
  const int tid = threadIdx.x;

  __shared__ int   slist[32];     // max 4 mentions * len<=5 = 20 positions
  __shared__ int   n_sh;
  __shared__ float ar[64][20];    // 80B row stride: float4-aligned, 8 banks

  // ---------------- Phase 1: be = bid (blocks 0..127) ----------------
  if (bid < Bc * Ec) {
    const int be = bid, b = be >> 4;

    { // zero this (b,e)'s ctxu slice
      float* z = ctxu + (size_t)be * Hc;
      z[tid] = 0.f; z[tid + 256] = 0.f; z[tid + 512] = 0.f;
    }

    if (tid == 0) n_sh = 0;
    __syncthreads();
    const int base = be * Mc;
    const int st0 = starts[base+0], st1 = starts[base+1];
    const int st2 = starts[base+2], st3 = starts[base+3];
    const int en0 = st0 + lens[base+0], en1 = st1 + lens[base+1];
    const int en2 = st2 + lens[base+2], en3 = st3 + lens[base+3];
    for (int s = tid; s < Sc; s += 256) {
      bool in = (s > st0 && s <= en0) || (s > st1 && s <= en1) ||
                (s > st2 && s <= en2) || (s > st3 && s <= en3);
      if (in) { int pos = atomicAdd(&n_sh, 1); slist[pos] = s; }
    }
    __syncthreads();
    const int n = n_sh;           // guaranteed >= 1

    // att_rows[be][t] = sum over masked s of attention[b][s][t] (4-way MLP)
    {
      const float2* a2 = (const float2*)(att + (size_t)b * Sc * Sc);
      float2 acc2 = make_float2(0.f, 0.f);
      int i = 0;
      for (; i + 4 <= n; i += 4) {
        float2 v0 = a2[(size_t)slist[i+0] * (Sc/2) + tid];
        float2 v1 = a2[(size_t)slist[i+1] * (Sc/2) + tid];
        float2 v2 = a2[(size_t)slist[i+2] * (Sc/2) + tid];
        float2 v3 = a2[(size_t)slist[i+3] * (Sc/2) + tid];
        acc2.x += (v0.x + v1.x) + (v2.x + v3.x);
        acc2.y += (v0.y + v1.y) + (v2.y + v3.y);
      }
      for (; i < n; ++i) {
        float2 v = a2[(size_t)slist[i] * (Sc/2) + tid];
        acc2.x += v.x; acc2.y += v.y;
      }
      ((float2*)(att_rows + (size_t)be * Sc))[tid] = acc2;
      if (tid == 0) cnt[be] = (float)n;
    }

    // doc[be][h] = logsumexp over masked s (two-pass: max then sum-exp)
    #pragma unroll
    for (int kk = 0; kk < 3; ++kk) {
      const int h = tid + kk * 256;
      const float* ecol = emb + (size_t)b * Sc * Hc + h;
      float m0 = -3.4e38f, m1 = -3.4e38f, m2 = -3.4e38f, m3 = -3.4e38f;
      int ii = 0;
      for (; ii + 4 <= n; ii += 4) {
        m0 = fmaxf(m0, ecol[(size_t)slist[ii+0] * Hc]);
        m1 = fmaxf(m1, ecol[(size_t)slist[ii+1] * Hc]);
        m2 = fmaxf(m2, ecol[(size_t)slist[ii+2] * Hc]);
        m3 = fmaxf(m3, ecol[(size_t)slist[ii+3] * Hc]);
      }
      for (; ii < n; ++ii) m0 = fmaxf(m0, ecol[(size_t)slist[ii] * Hc]);
      const float m = fmaxf(fmaxf(m0, m1), fmaxf(m2, m3));
      float l0 = 0.f, l1 = 0.f, l2 = 0.f, l3 = 0.f;
      ii = 0;
      for (; ii + 4 <= n; ii += 4) {     // second pass: L1/L2-hot
        l0 += __expf(ecol[(size_t)slist[ii+0] * Hc] - m);
        l1 += __expf(ecol[(size_t)slist[ii+1] * Hc] - m);
        l2 += __expf(ecol[(size_t)slist[ii+2] * Hc] - m);
        l3 += __expf(ecol[(size_t)slist[ii+3] * Hc] - m);
      }
      for (; ii < n; ++ii) l0 += __expf(ecol[(size_t)slist[ii] * Hc] - m);
      docv[(size_t)be * Hc + h] = m + __logf((l0 + l1) + (l2 + l3));
    }
  }

  gg.sync();

  // ---------------- Phase 2: u = bid = b*24 + hchunk*8 + tchunk ----------
  {
    const int tchunk = bid & 7;          // 0..7  (64 t each)
    const int hb     = bid >> 3;         // 0..23
    const int hchunk = hb % 3;           // 0..2  (256 h each)
    const int b      = hb / 3;
    const int h  = hchunk * 256 + tid;
    const int t0 = tchunk * 64;

    {
      const int e = tid >> 4, q = tid & 15;   // 16 e * 16 float4
      const float4* src =
          (const float4*)(att_rows + ((size_t)(b * Ec + e)) * Sc + t0);
      float4 v = src[q];
      ar[q*4+0][e] = v.x;
      ar[q*4+1][e] = v.y;
      ar[q*4+2][e] = v.z;
      ar[q*4+3][e] = v.w;
    }
    __syncthreads();

    float acc[16];
    #pragma unroll
    for (int e = 0; e < 16; ++e) acc[e] = 0.f;

    const float* ecol = emb + ((size_t)b * Sc + t0) * Hc + h;
    #pragma unroll 8
    for (int tt = 0; tt < 64; ++tt) {
      float ev = ecol[(size_t)tt * Hc];
      const float4* arv = (const float4*)&ar[tt][0];   // broadcast b128
      float4 q0 = arv[0], q1 = arv[1], q2 = arv[2], q3 = arv[3];
      acc[ 0] = fmaf(q0.x, ev, acc[ 0]);
      acc[ 1] = fmaf(q0.y, ev, acc[ 1]);
      acc[ 2] = fmaf(q0.z, ev, acc[ 2]);
      acc[ 3] = fmaf(q0.w, ev, acc[ 3]);
      acc[ 4] = fmaf(q1.x, ev, acc[ 4]);
      acc[ 5] = fmaf(q1.y, ev, acc[ 5]);
      acc[ 6] = fmaf(q1.z, ev, acc[ 6]);
      acc[ 7] = fmaf(q1.w, ev, acc[ 7]);
      acc[ 8] = fmaf(q2.x, ev, acc[ 8]);
      acc[ 9] = fmaf(q2.y, ev, acc[ 9]);
      acc[10] = fmaf(q2.z, ev, acc[10]);
      acc[11] = fmaf(q2.w, ev, acc[11]);
      acc[12] = fmaf(q3.x, ev, acc[12]);
      acc[13] = fmaf(q3.y, ev, acc[13]);
      acc[14] = fmaf(q3.z, ev, acc[14]);
      acc[15] = fmaf(q3.w, ev, acc[15]);
    }

    float* outb = ctxu + (size_t)(b * Ec) * Hc + h;
    #pragma unroll
    for (int e = 0; e < 16; ++e) atomicAdd(outb + (size_t)e * Hc, acc[e]);
  }

  gg.sync();

  // ---------------- Phase 3: 10 consecutive rows per block ---------------
  const size_t lab_base = (size_t)Bc * Pc * 4 * Hc;
  for (int rr = 0; rr < 10; ++rr) {
    const int r = bid * 10 + rr;
    const int b = r / Pc, p = r % Pc;
    const int i = p / 15, kq = p % 15;
    const int j = kq + (kq >= i ? 1 : 0);

    const float4* cls4 = (const float4*)(emb  + (size_t)b * Sc * Hc);  // s=0
    const float4* di4  = (const float4*)(docv + (size_t)(b * Ec + i) * Hc);
    const float4* dj4  = (const float4*)(docv + (size_t)(b * Ec + j) * Hc);
    const float4* xi4  = (const float4*)(ctxu + (size_t)(b * Ec + i) * Hc);
    const float4* xj4  = (const float4*)(ctxu + (size_t)(b * Ec + j) * Hc);
    float4* o = (float4*)(out + (size_t)r * 4 * Hc);

    if (tid < 192) {
      const float ci = 1.0f / cnt[b * Ec + i];
      const float cj = 1.0f / cnt[b * Ec + j];
      o[      tid] = cls4[tid];
      o[192 + tid] = di4[tid];
      o[384 + tid] = dj4[tid];
      float4 xa = xi4[tid], xb = xj4[tid], c;
      c.x = (xa.x * ci) * (xb.x * cj);
      c.y = (xa.y * ci) * (xb.y * cj);
      c.z = (xa.z * ci) * (xb.z * cj);
      c.w = (xa.w * ci) * (xb.w * cj);
      o[576 + tid] = c;
    } else if (tid < 216) {
      const int q = tid - 192;          // 24 int4 = 96 labels
      const int4* l4 =
          (const int4*)(labels + (((size_t)b * Ec + i) * Ec + j) * Cc);
      int4 v = l4[q];
      float4 f;
      f.x = (float)v.x; f.y = (float)v.y; f.z = (float)v.z; f.w = (float)v.w;
      ((float4*)(out + lab_base + (size_t)r * Cc))[q] = f;
    }
  }
}

extern "C" void kernel_launch(void* const* d_in, const int* in_sizes, int n_in,
                              void* d_out, int out_size, void* d_ws, size_t ws_size,
                              hipStream_t stream) {
  const float* emb    = (const float*)d_in[0];
  const float* att    = (const float*)d_in[1];
  const int*   starts = (const int*)d_in[2];
  const int*   lens   = (const int*)d_in[3];
  const int*   labels = (const int*)d_in[4];
  float* out = (float*)d_out;

  float* att_rows = (float*)d_ws;
  float* cnt      = att_rows + (size_t)Bc * Ec * Sc;
  float* docv     = cnt      + (size_t)Bc * Ec;
  float* ctxu     = docv     + (size_t)Bc * Ec * Hc;

  void* args[] = {
    (void*)&emb, (void*)&att, (void*)&starts, (void*)&lens, (void*)&labels,
    (void*)&att_rows, (void*)&cnt, (void*)&docv, (void*)&ctxu, (void*)&out
  };
  hipLaunchCooperativeKernel((const void*)k_fused, dim3(NB), dim3(256),
                             args, 0, stream);
}

// Round 9
// 99.953 us; speedup vs baseline: 1.5598x; 1.5598x over previous
//
#include <hip/hip_runtime.h>
#include <math.h>

#define Bc 8
#define Sc 512
#define Hc 768
#define Ec 16
#define Mc 4
#define Cc 96
#define Pc 240   // E*E - E

// ws layout (floats):
//   att_rows : B*E*S = 65536
//   cnt      : B*E   = 128
//   docv     : B*E*H = 98304
//   ctxu     : B*E*H = 98304  (atomic-accumulated; zeroed by K1)

// ---------------------------------------------------------------------------
// K1: per (b,e) — mask compaction, count, att_rows (4-way MLP), doc
// logsumexp (two-pass), zero ctxu slice.  128 blocks x 256.
// ---------------------------------------------------------------------------
__global__ __launch_bounds__(256) void k_mask_att_doc(
    const float* __restrict__ emb, const float* __restrict__ att,
    const int* __restrict__ starts, const int* __restrict__ lens,
    float* __restrict__ att_rows, float* __restrict__ cnt,
    float* __restrict__ docv, float* __restrict__ ctxu)
{
  const int be = blockIdx.x;      // b*16 + e
  const int b  = be >> 4;
  const int tid = threadIdx.x;

  { // zero this (b,e)'s ctxu slice (K2 atomically accumulates into it)
    float* z = ctxu + (size_t)be * Hc;
    z[tid] = 0.f; z[tid + 256] = 0.f; z[tid + 512] = 0.f;
  }

  __shared__ int slist[32];       // max 4 mentions * len<=5 = 20 positions
  __shared__ int n_sh;
  if (tid == 0) n_sh = 0;
  __syncthreads();

  const int base = be * Mc;
  const int st0 = starts[base+0], st1 = starts[base+1];
  const int st2 = starts[base+2], st3 = starts[base+3];
  const int en0 = st0 + lens[base+0], en1 = st1 + lens[base+1];
  const int en2 = st2 + lens[base+2], en3 = st3 + lens[base+3];

  for (int s = tid; s < Sc; s += 256) {
    bool in = (s > st0 && s <= en0) || (s > st1 && s <= en1) ||
              (s > st2 && s <= en2) || (s > st3 && s <= en3);
    if (in) { int pos = atomicAdd(&n_sh, 1); slist[pos] = s; }
  }
  __syncthreads();
  const int n = n_sh;             // guaranteed >= 1

  // att_rows[be][t] = sum over masked s of attention[b][s][t] (4-way MLP)
  {
    const float2* a2 = (const float2*)(att + (size_t)b * Sc * Sc);
    float2 acc2 = make_float2(0.f, 0.f);
    int i = 0;
    for (; i + 4 <= n; i += 4) {
      float2 v0 = a2[(size_t)slist[i+0] * (Sc/2) + tid];
      float2 v1 = a2[(size_t)slist[i+1] * (Sc/2) + tid];
      float2 v2 = a2[(size_t)slist[i+2] * (Sc/2) + tid];
      float2 v3 = a2[(size_t)slist[i+3] * (Sc/2) + tid];
      acc2.x += (v0.x + v1.x) + (v2.x + v3.x);
      acc2.y += (v0.y + v1.y) + (v2.y + v3.y);
    }
    for (; i < n; ++i) {
      float2 v = a2[(size_t)slist[i] * (Sc/2) + tid];
      acc2.x += v.x; acc2.y += v.y;
    }
    ((float2*)(att_rows + (size_t)be * Sc))[tid] = acc2;
    if (tid == 0) cnt[be] = (float)n;
  }

  // doc[be][h] = logsumexp over masked s (two-pass; 2nd pass L1/L2-hot)
  #pragma unroll
  for (int kk = 0; kk < 3; ++kk) {
    const int h = tid + kk * 256;
    const float* ecol = emb + (size_t)b * Sc * Hc + h;
    float m0 = -3.4e38f, m1 = -3.4e38f, m2 = -3.4e38f, m3 = -3.4e38f;
    int ii = 0;
    for (; ii + 4 <= n; ii += 4) {
      m0 = fmaxf(m0, ecol[(size_t)slist[ii+0] * Hc]);
      m1 = fmaxf(m1, ecol[(size_t)slist[ii+1] * Hc]);
      m2 = fmaxf(m2, ecol[(size_t)slist[ii+2] * Hc]);
      m3 = fmaxf(m3, ecol[(size_t)slist[ii+3] * Hc]);
    }
    for (; ii < n; ++ii) m0 = fmaxf(m0, ecol[(size_t)slist[ii] * Hc]);
    const float m = fmaxf(fmaxf(m0, m1), fmaxf(m2, m3));
    float l0 = 0.f, l1 = 0.f, l2 = 0.f, l3 = 0.f;
    ii = 0;
    for (; ii + 4 <= n; ii += 4) {
      l0 += __expf(ecol[(size_t)slist[ii+0] * Hc] - m);
      l1 += __expf(ecol[(size_t)slist[ii+1] * Hc] - m);
      l2 += __expf(ecol[(size_t)slist[ii+2] * Hc] - m);
      l3 += __expf(ecol[(size_t)slist[ii+3] * Hc] - m);
    }
    for (; ii < n; ++ii) l0 += __expf(ecol[(size_t)slist[ii] * Hc] - m);
    docv[(size_t)be * Hc + h] = m + __logf((l0 + l1) + (l2 + l3));
  }
}

// ---------------------------------------------------------------------------
// K2: ctxu[b,e,h] += sum over 64-t-chunk of att_rows[b,e,t] * emb[b,t,h]
// grid (tchunk=8, hchunk=3, b=8) = 192 blocks; 16 e-accumulators/thread.
// emb read exactly once across the grid. LDS ar[64][20]: float4-aligned
// broadcast rows, staging spread over 8 banks.
// ---------------------------------------------------------------------------
__global__ __launch_bounds__(256) void k_context(
    const float* __restrict__ emb, const float* __restrict__ att_rows,
    float* __restrict__ ctxu)
{
  const int tchunk = blockIdx.x;  // 0..7  (64 t each)
  const int hchunk = blockIdx.y;  // 0..2  (256 h each)
  const int b      = blockIdx.z;
  const int tid = threadIdx.x;
  const int h  = hchunk * 256 + tid;
  const int t0 = tchunk * 64;

  __shared__ float ar[64][20];
  {
    const int e = tid >> 4, q = tid & 15;   // 16 e * 16 float4
    const float4* src =
        (const float4*)(att_rows + ((size_t)(b * Ec + e)) * Sc + t0);
    float4 v = src[q];
    ar[q*4+0][e] = v.x;
    ar[q*4+1][e] = v.y;
    ar[q*4+2][e] = v.z;
    ar[q*4+3][e] = v.w;
  }
  __syncthreads();

  float acc[16];
  #pragma unroll
  for (int e = 0; e < 16; ++e) acc[e] = 0.f;

  const float* ecol = emb + ((size_t)b * Sc + t0) * Hc + h;
  #pragma unroll 8
  for (int tt = 0; tt < 64; ++tt) {
    float ev = ecol[(size_t)tt * Hc];
    const float4* arv = (const float4*)&ar[tt][0];    // broadcast b128
    float4 q0 = arv[0], q1 = arv[1], q2 = arv[2], q3 = arv[3];
    acc[ 0] = fmaf(q0.x, ev, acc[ 0]);
    acc[ 1] = fmaf(q0.y, ev, acc[ 1]);
    acc[ 2] = fmaf(q0.z, ev, acc[ 2]);
    acc[ 3] = fmaf(q0.w, ev, acc[ 3]);
    acc[ 4] = fmaf(q1.x, ev, acc[ 4]);
    acc[ 5] = fmaf(q1.y, ev, acc[ 5]);
    acc[ 6] = fmaf(q1.z, ev, acc[ 6]);
    acc[ 7] = fmaf(q1.w, ev, acc[ 7]);
    acc[ 8] = fmaf(q2.x, ev, acc[ 8]);
    acc[ 9] = fmaf(q2.y, ev, acc[ 9]);
    acc[10] = fmaf(q2.z, ev, acc[10]);
    acc[11] = fmaf(q2.w, ev, acc[11]);
    acc[12] = fmaf(q3.x, ev, acc[12]);
    acc[13] = fmaf(q3.y, ev, acc[13]);
    acc[14] = fmaf(q3.z, ev, acc[14]);
    acc[15] = fmaf(q3.w, ev, acc[15]);
  }

  float* outb = ctxu + (size_t)(b * Ec) * Hc + h;
  #pragma unroll
  for (int e = 0; e < 16; ++e) atomicAdd(outb + (size_t)e * Hc, acc[e]);
}

// ---------------------------------------------------------------------------
// K3: assemble output, all float4. 1920 blocks x 256: waves 0-2 write the
// 4x768 feature row, wave 3 (lanes 0-23) writes labels concurrently.
// ---------------------------------------------------------------------------
__global__ __launch_bounds__(256) void k_assemble(
    const float* __restrict__ emb, const int* __restrict__ labels,
    const float* __restrict__ docv, const float* __restrict__ ctxu,
    const float* __restrict__ cnt, float* __restrict__ out)
{
  const int r = blockIdx.x;
  const int b = r / Pc, p = r % Pc;
  const int i = p / 15, k = p % 15;
  const int j = k + (k >= i ? 1 : 0);
  const int tid = threadIdx.x;

  if (tid < 192) {
    const float ci = 1.0f / cnt[b * Ec + i];
    const float cj = 1.0f / cnt[b * Ec + j];
    const float4* cls4 = (const float4*)(emb  + (size_t)b * Sc * Hc);  // s=0
    const float4* di4  = (const float4*)(docv + (size_t)(b * Ec + i) * Hc);
    const float4* dj4  = (const float4*)(docv + (size_t)(b * Ec + j) * Hc);
    const float4* xi4  = (const float4*)(ctxu + (size_t)(b * Ec + i) * Hc);
    const float4* xj4  = (const float4*)(ctxu + (size_t)(b * Ec + j) * Hc);
    float4* o = (float4*)(out + (size_t)r * 4 * Hc);

    o[      tid] = cls4[tid];
    o[192 + tid] = di4[tid];
    o[384 + tid] = dj4[tid];
    float4 xa = xi4[tid], xb = xj4[tid], c;
    c.x = (xa.x * ci) * (xb.x * cj);
    c.y = (xa.y * ci) * (xb.y * cj);
    c.z = (xa.z * ci) * (xb.z * cj);
    c.w = (xa.w * ci) * (xb.w * cj);
    o[576 + tid] = c;
  } else if (tid < 216) {
    const int q = tid - 192;        // 24 int4 = 96 labels
    const int4* l4 =
        (const int4*)(labels + (((size_t)b * Ec + i) * Ec + j) * Cc);
    int4 v = l4[q];
    float4 f;
    f.x = (float)v.x; f.y = (float)v.y; f.z = (float)v.z; f.w = (float)v.w;
    ((float4*)(out + (size_t)Bc * Pc * 4 * Hc + (size_t)r * Cc))[q] = f;
  }
}

extern "C" void kernel_launch(void* const* d_in, const int* in_sizes, int n_in,
                              void* d_out, int out_size, void* d_ws, size_t ws_size,
                              hipStream_t stream) {
  const float* emb    = (const float*)d_in[0];
  const float* att    = (const float*)d_in[1];
  const int*   starts = (const int*)d_in[2];
  const int*   lens   = (const int*)d_in[3];
  const int*   labels = (const int*)d_in[4];
  float* out = (float*)d_out;

  float* att_rows = (float*)d_ws;
  float* cnt      = att_rows + (size_t)Bc * Ec * Sc;
  float* docv     = cnt      + (size_t)Bc * Ec;
  float* ctxu     = docv     + (size_t)Bc * Ec * Hc;

  k_mask_att_doc<<<Bc * Ec, 256, 0, stream>>>(emb, att, starts, lens,
                                              att_rows, cnt, docv, ctxu);
  k_context<<<dim3(8, 3, Bc), 256, 0, stream>>>(emb, att_rows, ctxu);
  k_assemble<<<Bc * Pc, 256, 0, stream>>>(emb, labels, docv, ctxu, cnt, out);
}